// Round 4
// baseline (49.846 us; speedup 1.0000x reference)
//
#include <hip/hip_runtime.h>
#include <math.h>

#define BB 8
#define HH 256
#define WW 256
#define PAD 16
#define NROW (BB * HH)   // 2048 row-blocks

// Workspace layout (everything written unconditionally every call -> no
// memset node in the graph):
//   colbits : BB*WW*8 u32   = 65536 B   (u32 w covers rows 32w..32w+31)
//   blockany: BB*8    int   =   256 B
//   partial : NROW    double= 16384 B
//   counter : 1       int

// ---------------------------------------------------------------------------
// Kernel A: per-column occupancy bitmasks, 32 rows per block -> u32 words.
// Grid (BB, 8), 256 threads (one per column j). Row reads fully coalesced.
// Also resets the ticket counter (visible to kernel B at dispatch boundary).
// ---------------------------------------------------------------------------
__global__ void build_colbits_kernel(const int* __restrict__ targets,
                                     unsigned int* __restrict__ colbits,
                                     int* __restrict__ blockany,
                                     int* __restrict__ counter) {
    const int b = blockIdx.x;
    const int w = blockIdx.y;          // 0..7
    const int j = threadIdx.x;         // 0..255
    const int* t = targets + ((size_t)b * HH + 32 * w) * WW + j;
    unsigned int bits = 0u;
    #pragma unroll
    for (int r = 0; r < 32; ++r)
        bits |= (unsigned int)(t[r * WW] != 0) << r;
    colbits[((size_t)(b * WW + j) << 3) + w] = bits;

    __shared__ int anyw[4];
    const unsigned long long ba = __ballot(bits != 0u);
    if ((j & 63) == 0) anyw[j >> 6] = (ba != 0ull) ? 1 : 0;
    __syncthreads();
    if (j == 0)
        blockany[b * 8 + w] = anyw[0] | anyw[1] | anyw[2] | anyw[3];
    if (b == 0 && w == 0 && j == 0)
        *counter = 0;                  // ticket reset, each call
}

// ---------------------------------------------------------------------------
// Vertical 1D distance from the 256-bit column mask (exact reference scan
// semantics): d(i) = min( i - prev_set, next_set - i, i + 513, 768 - i ).
// ---------------------------------------------------------------------------
__device__ __forceinline__ float col_dist(unsigned long long w0, unsigned long long w1,
                                          unsigned long long w2, unsigned long long w3,
                                          int i) {
    const int INF = 1 << 20;
    int best = min(i + 513, 768 - i);
    const unsigned long long ws[4] = {w0, w1, w2, w3};
    #pragma unroll
    for (int k = 0; k < 4; ++k) {
        const unsigned long long wk = ws[k];
        const int rel = i - 64 * k;
        {
            const int sh = min(max(rel, 0), 63);
            const unsigned long long m = (rel < 64) ? (wk >> sh) : 0ull;
            const int d = m ? (__ffsll((unsigned long long)m) - 1 + sh - rel) : INF;
            best = min(best, d);
        }
        {
            const int sh = min(max(63 - rel, 0), 63);
            const unsigned long long m = (rel >= 0) ? (wk << sh) : 0ull;
            const int add = rel > 63 ? rel - 63 : 0;
            const int d = m ? (__clzll((long long)m) + add) : INF;
            best = min(best, d);
        }
    }
    return (float)best;
}

// ---------------------------------------------------------------------------
// Kernel B: one block per row (b, i). Each pixel needs only ONE distance
// field (in-mask -> dist_in, background -> dist_out; the other is 0).
// Exact windowed min-plus: d2[j] <= h[j] := g2_sel[j], so |j-l| > R with
// R = floor(sqrt(max_j h[j])) + 1 cannot improve the min. Window is
// block-uniform; LDS padded +-16 with 1e30 so no clamps; uniform full-scan
// fallback if R > 16 keeps exactness for any input. Last block (device-scope
// ticket) reduces the 2048 partials and writes the final scalar.
// ---------------------------------------------------------------------------
__global__ void fused_row_kernel(const float* __restrict__ logits,
                                 const unsigned long long* __restrict__ colbits,
                                 const int* __restrict__ blockany,
                                 double* __restrict__ partial,
                                 int* __restrict__ counter,
                                 float* __restrict__ out) {
    const int row = blockIdx.x;        // b*HH + i
    const int b = row >> 8;
    const int i = row & 255;
    const int j = threadIdx.x;
    const int lane = j & 63;
    const int wid  = j >> 6;

    __shared__ __align__(16) float so[WW + 2 * PAD];
    __shared__ __align__(16) float si[WW + 2 * PAD];
    __shared__ float hred[4];
    __shared__ double wsum[4];
    __shared__ int lastflag;

    const unsigned long long* cb = colbits + ((size_t)(b * WW + j) << 2);
    const unsigned long long w0 = cb[0], w1 = cb[1], w2 = cb[2], w3 = cb[3];
    const float x = logits[(size_t)row * WW + j];   // issue early

    const bool m = ((w1 >> (i & 63)) & ((w3 >> (i & 63))) , false) ? false
                 : (((i < 64 ? w0 : i < 128 ? w1 : i < 192 ? w2 : w3) >> (i & 63)) & 1ull) != 0ull;

    const float go = col_dist(w0, w1, w2, w3, i);
    const float gi = col_dist(~w0, ~w1, ~w2, ~w3, i);
    const float go2 = go * go, gi2 = gi * gi;     // exact integers in f32
    so[PAD + j] = go2;
    si[PAD + j] = gi2;
    if (j < PAD) {
        so[j] = 1e30f; si[j] = 1e30f;
        so[PAD + WW + j] = 1e30f; si[PAD + WW + j] = 1e30f;
    }

    // h = ceiling for the field this pixel actually needs
    const float h = m ? gi2 : go2;
    float hmax = h;
    #pragma unroll
    for (int off = 32; off > 0; off >>= 1)
        hmax = fmaxf(hmax, __shfl_xor(hmax, off, 64));
    if (lane == 0) hred[wid] = hmax;
    __syncthreads();                   // covers so/si/pad writes + hred
    hmax = fmaxf(fmaxf(hred[0], hred[1]), fmaxf(hred[2], hred[3]));
    const int R = (int)sqrtf(hmax) + 1;

    const float* s = (m ? si : so) + PAD;
    float d2 = 1e30f;
    if (R <= PAD) {                    // windowed exact scan (normal path)
        const float* sw = s + j - R;
        float df = (float)R;
        for (int k = 0; k <= 2 * R; ++k) {
            d2 = fminf(d2, fmaf(df, df, sw[k]));
            df -= 1.0f;
        }
    } else {                           // uniform fallback: full exact scan
        float df = (float)j;
        #pragma unroll 4
        for (int l = 0; l < WW; ++l) {
            d2 = fminf(d2, fmaf(df, df, s[l]));
            df -= 1.0f;
        }
    }

    const double sd = sqrt((double)d2);
    const double sdf = m ? -sd : sd;                 // dist_out - dist_in
    const double p  = 1.0 / (1.0 + exp(-(double)x));
    double c = p * sdf;

    #pragma unroll
    for (int off = 32; off > 0; off >>= 1)
        c += __shfl_down(c, off, 64);
    if (lane == 0) wsum[wid] = c;
    __syncthreads();

    if (j == 0) {
        const double total = wsum[0] + wsum[1] + wsum[2] + wsum[3];
        __hip_atomic_store(&partial[row], total, __ATOMIC_RELAXED,
                           __HIP_MEMORY_SCOPE_AGENT);
        __threadfence();               // release partial before ticket
        const int t = atomicAdd(counter, 1);
        lastflag = (t == NROW - 1);
    }
    __syncthreads();

    if (lastflag) {                    // last block: final reduction
        __threadfence();               // acquire
        double s2 = 0.0;
        #pragma unroll
        for (int bb = 0; bb < BB; ++bb) {
            int f = 0;
            #pragma unroll
            for (int w = 0; w < 8; ++w) f |= blockany[bb * 8 + w];
            const double v = __hip_atomic_load(&partial[bb * HH + j],
                                               __ATOMIC_RELAXED,
                                               __HIP_MEMORY_SCOPE_AGENT);
            s2 += f ? v : 0.0;
        }
        #pragma unroll
        for (int off = 32; off > 0; off >>= 1)
            s2 += __shfl_down(s2, off, 64);
        if (lane == 0) wsum[wid] = s2;
        __syncthreads();
        if (j == 0)
            out[0] = (float)((wsum[0] + wsum[1] + wsum[2] + wsum[3])
                             / (double)((long long)BB * HH * WW));
    }
}

extern "C" void kernel_launch(void* const* d_in, const int* in_sizes, int n_in,
                              void* d_out, int out_size, void* d_ws, size_t ws_size,
                              hipStream_t stream) {
    const float* logits  = (const float*)d_in[0];
    const int*   targets = (const int*)d_in[1];
    float*       out     = (float*)d_out;

    char* ws = (char*)d_ws;
    const size_t off_bits = 0;                                    // 64 KB
    const size_t off_any  = (size_t)BB * WW * 8 * sizeof(unsigned int);
    const size_t off_par  = off_any + 256;
    const size_t off_cnt  = off_par + (size_t)NROW * sizeof(double);

    unsigned int* colbits  = (unsigned int*)(ws + off_bits);
    int*          blockany = (int*)(ws + off_any);
    double*       partial  = (double*)(ws + off_par);
    int*          counter  = (int*)(ws + off_cnt);

    build_colbits_kernel<<<dim3(BB, 8), WW, 0, stream>>>(targets, colbits,
                                                         blockany, counter);
    fused_row_kernel<<<NROW, WW, 0, stream>>>(logits,
                                              (const unsigned long long*)colbits,
                                              blockany, partial, counter, out);
}

// Round 5
// 18.447 us; speedup vs baseline: 2.7021x; 2.7021x over previous
//
#include <hip/hip_runtime.h>
#include <math.h>

#define BB 8
#define HH 256
#define WW 256
#define PAD 16
#define LDSW (WW + 2 * PAD + 4)   // 292: +4 so field rows land on offset banks
#define NROW (BB * HH)

// Workspace layout (all slots written unconditionally every call -> no
// memset node in the graph):
//   colbits : BB*WW*8 u32   = 65536 B   (u32 word w covers rows 32w..32w+31)
//   blockany: BB*8    int   =   256 B
//   partial : NROW    double= 16384 B

// ---------------------------------------------------------------------------
// Kernel A: per-column occupancy bitmasks, 32 rows per block -> u32 words.
// Grid (BB, 8), 256 threads (one per column j). Row reads fully coalesced.
// ---------------------------------------------------------------------------
__global__ void build_colbits_kernel(const int* __restrict__ targets,
                                     unsigned int* __restrict__ colbits,
                                     int* __restrict__ blockany) {
    const int b = blockIdx.x;
    const int w = blockIdx.y;          // 0..7
    const int j = threadIdx.x;         // 0..255
    const int* t = targets + ((size_t)b * HH + 32 * w) * WW + j;
    unsigned int bits = 0u;
    #pragma unroll
    for (int r = 0; r < 32; ++r)
        bits |= (unsigned int)(t[r * WW] != 0) << r;
    colbits[((size_t)(b * WW + j) << 3) + w] = bits;

    __shared__ int anyw[4];
    const unsigned long long ba = __ballot(bits != 0u);
    if ((j & 63) == 0) anyw[j >> 6] = (ba != 0ull) ? 1 : 0;
    __syncthreads();
    if (j == 0)
        blockany[b * 8 + w] = anyw[0] | anyw[1] | anyw[2] | anyw[3];
}

// ---------------------------------------------------------------------------
// Vertical 1D distance from the 256-bit column mask (exact reference scan
// semantics): d(i) = min( i - prev_set, next_set - i, i + 513, 768 - i ).
// i is block-uniform -> shifts are SALU; k is compile-time.
// ---------------------------------------------------------------------------
__device__ __forceinline__ float col_dist(unsigned long long w0, unsigned long long w1,
                                          unsigned long long w2, unsigned long long w3,
                                          int i) {
    const int INF = 1 << 20;
    int best = min(i + 513, 768 - i);
    const unsigned long long ws[4] = {w0, w1, w2, w3};
    #pragma unroll
    for (int k = 0; k < 4; ++k) {
        const unsigned long long wk = ws[k];
        const int rel = i - 64 * k;
        {
            const int sh = min(max(rel, 0), 63);
            const unsigned long long m = (rel < 64) ? (wk >> sh) : 0ull;
            const int d = m ? (__ffsll((unsigned long long)m) - 1 + sh - rel) : INF;
            best = min(best, d);
        }
        {
            const int sh = min(max(63 - rel, 0), 63);
            const unsigned long long m = (rel >= 0) ? (wk << sh) : 0ull;
            const int add = rel > 63 ? rel - 63 : 0;
            const int d = m ? (__clzll((long long)m) + add) : INF;
            best = min(best, d);
        }
    }
    return (float)best;
}

// ---------------------------------------------------------------------------
// Kernel B: one block per row (b, i), 256 threads (one per column j).
// Each pixel needs only ONE field (in-mask -> dist_in, else dist_out).
// Exact fixed window: d2[j] <= h[j] := g2_sel[j] (the l=j candidate), so the
// argmin l* obeys (j-l*)^2 <= hmax. If hmax <= 288 (exact integer compare)
// then |j-l*| <= 16 and the FULLY UNROLLED 33-wide scan is exact; otherwise
// take the uniform full-scan fallback. Pads hold 1e30 sentinels.
// ---------------------------------------------------------------------------
__global__ void fused_row_kernel(const float* __restrict__ logits,
                                 const unsigned long long* __restrict__ colbits,
                                 double* __restrict__ partial) {
    const int row = blockIdx.x;        // b*HH + i
    const int b = row >> 8;
    const int i = row & 255;
    const int j = threadIdx.x;
    const int lane = j & 63;
    const int wid  = j >> 6;

    __shared__ __align__(16) float sbuf[2][LDSW];   // [0]=out field, [1]=in field
    __shared__ float hred[4];
    __shared__ double wsum[4];

    const unsigned long long* cb = colbits + ((size_t)(b * WW + j) << 2);
    const unsigned long long w0 = cb[0], w1 = cb[1], w2 = cb[2], w3 = cb[3];
    const float x = logits[(size_t)row * WW + j];   // issue early

    const unsigned long long wsel = (i < 64) ? w0 : (i < 128) ? w1 : (i < 192) ? w2 : w3;
    const bool m = ((wsel >> (i & 63)) & 1ull) != 0ull;

    const float go = col_dist(w0, w1, w2, w3, i);
    const float gi = col_dist(~w0, ~w1, ~w2, ~w3, i);
    const float go2 = go * go, gi2 = gi * gi;       // exact integers in f32
    sbuf[0][PAD + j] = go2;
    sbuf[1][PAD + j] = gi2;
    if (j < PAD) {
        sbuf[0][j] = 1e30f;            sbuf[1][j] = 1e30f;
        sbuf[0][PAD + WW + j] = 1e30f; sbuf[1][PAD + WW + j] = 1e30f;
    }

    // hmax = max over row of the per-pixel ceiling h = g2 of the needed field
    float hmax = m ? gi2 : go2;
    #pragma unroll
    for (int off = 32; off > 0; off >>= 1)
        hmax = fmaxf(hmax, __shfl_xor(hmax, off, 64));
    if (lane == 0) hred[wid] = hmax;
    __syncthreads();                   // covers sbuf + pads + hred
    hmax = fmaxf(fmaxf(hred[0], hred[1]), fmaxf(hred[2], hred[3]));

    const float* s = &sbuf[m ? 1 : 0][PAD];
    float d2 = 1e30f;
    if (hmax <= 288.0f) {              // exact: |j - argmin| <= 16
        const float* sw = s + j - PAD;
        float df = (float)PAD;
        #pragma unroll
        for (int k = 0; k <= 2 * PAD; ++k) {
            d2 = fminf(d2, fmaf(df, df, sw[k]));
            df -= 1.0f;
        }
    } else {                           // uniform fallback: full exact scan
        float df = (float)j;
        #pragma unroll 8
        for (int l = 0; l < WW; ++l) {
            d2 = fminf(d2, fmaf(df, df, s[l]));
            df -= 1.0f;
        }
    }

    const double sd = sqrt((double)d2);
    const double sdf = m ? -sd : sd;                // dist_out - dist_in
    const double p  = 1.0 / (1.0 + exp(-(double)x));
    double c = p * sdf;

    #pragma unroll
    for (int off = 32; off > 0; off >>= 1)
        c += __shfl_down(c, off, 64);
    if (lane == 0) wsum[wid] = c;
    __syncthreads();
    if (j == 0)
        partial[row] = wsum[0] + wsum[1] + wsum[2] + wsum[3];   // no atomics
}

// ---------------------------------------------------------------------------
// Kernel C: finalize. 1 block x 256 threads; thread t sums partial[b*256+t]
// gated by batch-any flag; shuffle+LDS reduce; single write to out.
// ---------------------------------------------------------------------------
__global__ void finalize_kernel(const double* __restrict__ partial,
                                const int* __restrict__ blockany,
                                float* __restrict__ out) {
    const int t = threadIdx.x;         // 0..255
    double s = 0.0;
    #pragma unroll
    for (int b = 0; b < BB; ++b) {
        int f = 0;
        #pragma unroll
        for (int w = 0; w < 8; ++w) f |= blockany[b * 8 + w];
        const double v = partial[b * HH + t];
        s += f ? v : 0.0;
    }
    #pragma unroll
    for (int off = 32; off > 0; off >>= 1)
        s += __shfl_down(s, off, 64);
    __shared__ double wsum[4];
    if ((t & 63) == 0) wsum[t >> 6] = s;
    __syncthreads();
    if (t == 0)
        out[0] = (float)((wsum[0] + wsum[1] + wsum[2] + wsum[3])
                         / (double)((long long)BB * HH * WW));
}

extern "C" void kernel_launch(void* const* d_in, const int* in_sizes, int n_in,
                              void* d_out, int out_size, void* d_ws, size_t ws_size,
                              hipStream_t stream) {
    const float* logits  = (const float*)d_in[0];
    const int*   targets = (const int*)d_in[1];
    float*       out     = (float*)d_out;

    char* ws = (char*)d_ws;
    const size_t off_bits = 0;                                    // 64 KB
    const size_t off_any  = (size_t)BB * WW * 8 * sizeof(unsigned int);
    const size_t off_par  = off_any + 256;

    unsigned int* colbits  = (unsigned int*)(ws + off_bits);
    int*          blockany = (int*)(ws + off_any);
    double*       partial  = (double*)(ws + off_par);

    build_colbits_kernel<<<dim3(BB, 8), WW, 0, stream>>>(targets, colbits, blockany);
    fused_row_kernel<<<NROW, WW, 0, stream>>>(logits,
                                              (const unsigned long long*)colbits,
                                              partial);
    finalize_kernel<<<1, WW, 0, stream>>>(partial, blockany, out);
}